// Round 2
// baseline (139.602 us; speedup 1.0000x reference)
//
#include <hip/hip_runtime.h>
#include <math.h>

// Problem constants (fixed by setup_inputs)
#define BB 4
#define DD 256
#define NN 65536      // H*W
#define CC 16
#define PP 5
#define CP 80         // C*P
#define EPSV 1e-10f

// ws layout (floats):
//   protosN : [0, 20480)
//   plane   : [20480, 20480+1310720)          e1 then overwritten by u (B*P*N)
//   denom1  : [1331200, +320)
//   denom2  : +320
//   cnt     : +64
//   Bbins   : +1600  (B*C*25)
#define OFF_PLANE  20480
#define OFF_ACC    1331200
#define ACC_FLOATS 2304   // 320+320+64+1600

__global__ void k_zero(float* __restrict__ acc) {
    for (int i = threadIdx.x; i < ACC_FLOATS; i += 256) acc[i] = 0.f;
}

__global__ void k_norm_protos(const float* __restrict__ protos,
                              float* __restrict__ protosN) {
    int r = blockIdx.x;          // 0..79
    int d = threadIdx.x;         // 0..255
    float v = protos[r * DD + d];
    __shared__ float red[256];
    red[d] = v * v;
    __syncthreads();
    for (int s = 128; s > 0; s >>= 1) {
        if (d < s) red[d] += red[d + s];
        __syncthreads();
    }
    float inv = 1.f / fmaxf(sqrtf(red[0]), 1e-12f);
    protosN[r * DD + d] = v * inv;
}

// Pass 1: per-pixel normalized dot with its class's 5 prototypes.
// e1 = exp(sim - 1) stored to plane[(b*P+p)*N + n]; denom1[b][c][p] += e1; cnt[b][c] += 1.
__global__ __launch_bounds__(256) void k_sims(const float* __restrict__ fmap,
                                              const float* __restrict__ protosN,
                                              const int* __restrict__ gt,
                                              float* __restrict__ plane,
                                              float* __restrict__ denom1,
                                              float* __restrict__ cnt) {
    __shared__ __align__(16) float lp[CP * 68];   // [cp][dl], 64-d chunk, pad 68
    __shared__ float bins[CP];
    __shared__ float binc[CC];
    const int tid = threadIdx.x;
    const int bx  = blockIdx.x;          // 1024 blocks: 256 per batch
    const int b   = bx >> 8;
    const int n   = ((bx & 255) << 8) + tid;

    if (tid < CP) bins[tid] = 0.f;
    if (tid < CC) binc[tid] = 0.f;

    const int c = gt[(size_t)b * NN + n];
    const float* fb = fmap + (size_t)b * DD * NN + n;

    float dot[PP] = {0.f, 0.f, 0.f, 0.f, 0.f};
    float norm2 = 0.f;

    for (int ch = 0; ch < 4; ++ch) {
        __syncthreads();   // protect lp reuse (and bins init on first iter)
        for (int idx = tid; idx < CP * 64; idx += 256) {
            int cp = idx >> 6, dl = idx & 63;
            lp[cp * 68 + dl] = protosN[cp * 256 + ch * 64 + dl];
        }
        __syncthreads();
        const float* lbase = lp + c * (PP * 68);
        for (int dl4 = 0; dl4 < 64; dl4 += 4) {
            float pvf[PP][4];
            #pragma unroll
            for (int p = 0; p < PP; ++p) {
                float4 t = *reinterpret_cast<const float4*>(&lbase[p * 68 + dl4]);
                pvf[p][0] = t.x; pvf[p][1] = t.y; pvf[p][2] = t.z; pvf[p][3] = t.w;
            }
            #pragma unroll
            for (int k = 0; k < 4; ++k) {
                float f = fb[(size_t)(ch * 64 + dl4 + k) * NN];
                norm2 = fmaf(f, f, norm2);
                #pragma unroll
                for (int p = 0; p < PP; ++p)
                    dot[p] = fmaf(f, pvf[p][k], dot[p]);
            }
        }
    }

    const float inv = 1.f / fmaxf(sqrtf(norm2), 1e-12f);
    #pragma unroll
    for (int p = 0; p < PP; ++p) {
        float e1 = expf(dot[p] * inv - 1.f);   // fixed shift: sims in [-1,1]
        plane[(size_t)(b * PP + p) * NN + n] = e1;
        atomicAdd(&bins[c * PP + p], e1);
    }
    atomicAdd(&binc[c], 1.f);
    __syncthreads();
    if (tid < CP) atomicAdd(&denom1[b * CP + tid], bins[tid]);
    if (tid < CC) atomicAdd(&cnt[b * CC + tid], binc[tid]);
}

// Pass 2: s1 = e1/denom1; u = exp(s1 - 1) (s1 in (0,1], fixed shift); denom2 += u.
__global__ __launch_bounds__(256) void k_s2(const int* __restrict__ gt,
                                            float* __restrict__ plane,
                                            const float* __restrict__ denom1,
                                            float* __restrict__ denom2) {
    __shared__ float inv1s[CP];
    __shared__ float bins[CP];
    const int tid = threadIdx.x;
    const int bx  = blockIdx.x;
    const int b   = bx >> 8;
    const int n   = ((bx & 255) << 8) + tid;
    if (tid < CP) { inv1s[tid] = 1.f / denom1[b * CP + tid]; bins[tid] = 0.f; }
    __syncthreads();
    const int c = gt[(size_t)b * NN + n];
    #pragma unroll
    for (int p = 0; p < PP; ++p) {
        size_t idx = (size_t)(b * PP + p) * NN + n;
        float u = expf(plane[idx] * inv1s[c * PP + p] - 1.f);
        plane[idx] = u;
        atomicAdd(&bins[c * PP + p], u);
    }
    __syncthreads();
    if (tid < CP) atomicAdd(&denom2[b * CP + tid], bins[tid]);
}

// Pass 3: V = u/denom2 + EPS; L = log(V); Bbins[b][c][i][j] += L[i]*V[j].
// (A[p] == Bbins[p][p]; all EPS-only terms cancel in J.)
__global__ __launch_bounds__(256) void k_bmat(const int* __restrict__ gt,
                                              const float* __restrict__ plane,
                                              const float* __restrict__ denom2,
                                              float* __restrict__ Bbins) {
    __shared__ float inv2s[CP];
    __shared__ float binsB[CC * 25];
    const int tid = threadIdx.x;
    const int bx  = blockIdx.x;
    const int b   = bx >> 8;
    const int n   = ((bx & 255) << 8) + tid;
    if (tid < CP) inv2s[tid] = 1.f / denom2[b * CP + tid];
    for (int i = tid; i < CC * 25; i += 256) binsB[i] = 0.f;
    __syncthreads();
    const int c = gt[(size_t)b * NN + n];
    float V[PP], L[PP];
    #pragma unroll
    for (int p = 0; p < PP; ++p) {
        float u = plane[(size_t)(b * PP + p) * NN + n];
        V[p] = fmaf(u, inv2s[c * PP + p], EPSV);
        L[p] = logf(V[p]);
    }
    float* bb = &binsB[c * 25];
    #pragma unroll
    for (int i = 0; i < PP; ++i)
        #pragma unroll
        for (int j = 0; j < PP; ++j)
            atomicAdd(&bb[i * 5 + j], L[i] * V[j]);
    __syncthreads();
    for (int i = tid; i < CC * 25; i += 256) atomicAdd(&Bbins[b * CC * 25 + i], binsB[i]);
}

__global__ void k_final(const float* __restrict__ Bbins,
                        const float* __restrict__ cnt,
                        float* __restrict__ out) {
    __shared__ float cs[BB * CC];
    __shared__ float pr[BB * CC];
    const int t = threadIdx.x;
    if (t < BB * CC) {
        const float* bb = &Bbins[t * 25];
        float s = 0.f;
        #pragma unroll
        for (int i = 0; i < PP; ++i)
            for (int j = i + 1; j < PP; ++j) {
                float J = bb[i * 5 + i] + bb[j * 5 + j] - bb[i * 5 + j] - bb[j * 5 + i];
                s += expf(-J);
            }
        bool present = cnt[t] > 0.f;
        cs[t] = present ? s * 0.1f : 0.f;   // / num_pairs (=10)
        pr[t] = present ? 1.f : 0.f;
    }
    __syncthreads();
    if (t == 0) {
        float total = 0.f;
        for (int b = 0; b < BB; ++b) {
            float sc = 0.f, np = 0.f;
            for (int c = 0; c < CC; ++c) { sc += cs[b * CC + c]; np += pr[b * CC + c]; }
            total += (np > 0.f) ? sc / np : 0.f;
        }
        out[0] = total / (float)BB;
    }
}

extern "C" void kernel_launch(void* const* d_in, const int* in_sizes, int n_in,
                              void* d_out, int out_size, void* d_ws, size_t ws_size,
                              hipStream_t stream) {
    const float* fmap   = (const float*)d_in[0];
    const float* protos = (const float*)d_in[1];
    const int*   gt     = (const int*)d_in[2];
    float* ws      = (float*)d_ws;
    float* protosN = ws;
    float* plane   = ws + OFF_PLANE;
    float* acc     = ws + OFF_ACC;
    float* denom1  = acc;
    float* denom2  = acc + 320;
    float* cnt     = acc + 640;
    float* Bbins   = acc + 704;
    float* out     = (float*)d_out;

    k_zero<<<1, 256, 0, stream>>>(acc);
    k_norm_protos<<<CP, 256, 0, stream>>>(protos, protosN);
    k_sims<<<BB * (NN / 256), 256, 0, stream>>>(fmap, protosN, gt, plane, denom1, cnt);
    k_s2<<<BB * (NN / 256), 256, 0, stream>>>(gt, plane, denom1, denom2);
    k_bmat<<<BB * (NN / 256), 256, 0, stream>>>(gt, plane, denom2, Bbins);
    k_final<<<1, 64, 0, stream>>>(Bbins, cnt, out);
}

// Round 3
// 100.432 us; speedup vs baseline: 1.3900x; 1.3900x over previous
//
#include <hip/hip_runtime.h>
#include <math.h>

// Problem constants (fixed by setup_inputs)
#define BB 4
#define DD 256
#define NN 65536      // H*W
#define CC 16
#define PP 5
#define CP 80         // C*P
#define EPSV 1e-10f
#define LPAD 68       // LDS proto row pitch (floats), breaks pow2 strides

// ws layout (floats):
//   protosN : [0, 20480)
//   plane   : [20480, +B*P*N)
//   acc     : denom1[320] denom2[320] cnt[64] Bbins[B*C*16=1024]
#define OFF_PLANE  20480
#define OFF_ACC    (OFF_PLANE + BB * PP * NN)
#define ACC_FLOATS (320 + 320 + 64 + BB * CC * 16)

// blocks 0..79: normalize prototype rows; block 80: zero accumulators
__global__ void k_norm(const float* __restrict__ protos,
                       float* __restrict__ protosN,
                       float* __restrict__ acc) {
    if (blockIdx.x == CP) {
        for (int i = threadIdx.x; i < ACC_FLOATS; i += 256) acc[i] = 0.f;
        return;
    }
    int r = blockIdx.x;
    int d = threadIdx.x;
    float v = protos[r * DD + d];
    __shared__ float red[256];
    red[d] = v * v;
    __syncthreads();
    for (int s = 128; s > 0; s >>= 1) {
        if (d < s) red[d] += red[d + s];
        __syncthreads();
    }
    float inv = 1.f / fmaxf(sqrtf(red[0]), 1e-12f);
    protosN[r * DD + d] = v * inv;
}

// Pass 1: per-pixel normalized dot with its class's 5 prototypes.
// 2 pixels/thread (float2 fmap loads), 4 d-chunks of 64, double-buffered LDS
// protos with async-stage split (issue loads early, ds_write late).
__global__ __launch_bounds__(256) void k_sims(const float* __restrict__ fmap,
                                              const float* __restrict__ protosN,
                                              const int* __restrict__ gt,
                                              float* __restrict__ plane,
                                              float* __restrict__ denom1,
                                              float* __restrict__ cnt) {
    __shared__ __align__(16) float lp[2][CP * LPAD];   // 2 x 21.76 KB
    __shared__ float bins[CP];
    __shared__ float binc[CC];
    const int tid = threadIdx.x;
    const int b   = blockIdx.x >> 7;                   // 512 blocks: 128/batch
    const int n0  = ((blockIdx.x & 127) << 9) + (tid << 1);

    if (tid < CP) bins[tid] = 0.f;
    if (tid < CC) binc[tid] = 0.f;

    const int2 cls = *reinterpret_cast<const int2*>(&gt[(size_t)b * NN + n0]);
    const float* fb = fmap + (size_t)b * DD * NN + n0;

    // stage chunk 0: global -> reg -> LDS
    float4 stg[5];
    #pragma unroll
    for (int r = 0; r < 5; ++r) {
        int idx = (r << 8) + tid;   // 0..1279 : cp = idx>>4, d4 = (idx&15)*4
        stg[r] = *reinterpret_cast<const float4*>(
            &protosN[(idx >> 4) * DD + ((idx & 15) << 2)]);
    }
    #pragma unroll
    for (int r = 0; r < 5; ++r) {
        int idx = (r << 8) + tid;
        *reinterpret_cast<float4*>(&lp[0][(idx >> 4) * LPAD + ((idx & 15) << 2)]) = stg[r];
    }
    __syncthreads();

    float dot0[PP] = {0.f, 0.f, 0.f, 0.f, 0.f};
    float dot1[PP] = {0.f, 0.f, 0.f, 0.f, 0.f};
    float nrm0 = 0.f, nrm1 = 0.f;

    for (int ch = 0; ch < 4; ++ch) {
        const int cur = ch & 1;
        // T14: issue next chunk's global loads before compute
        if (ch < 3) {
            #pragma unroll
            for (int r = 0; r < 5; ++r) {
                int idx = (r << 8) + tid;
                stg[r] = *reinterpret_cast<const float4*>(
                    &protosN[(idx >> 4) * DD + (ch + 1) * 64 + ((idx & 15) << 2)]);
            }
        }
        const float* lb0 = &lp[cur][cls.x * (PP * LPAD)];
        const float* lb1 = &lp[cur][cls.y * (PP * LPAD)];
        const float* fch = fb + (size_t)(ch * 64) * NN;
        #pragma unroll 2
        for (int dl4 = 0; dl4 < 64; dl4 += 4) {
            float4 pv0[PP], pv1[PP];
            #pragma unroll
            for (int p = 0; p < PP; ++p) {
                pv0[p] = *reinterpret_cast<const float4*>(&lb0[p * LPAD + dl4]);
                pv1[p] = *reinterpret_cast<const float4*>(&lb1[p * LPAD + dl4]);
            }
            #pragma unroll
            for (int k = 0; k < 4; ++k) {
                const float2 f = *reinterpret_cast<const float2*>(&fch[(size_t)(dl4 + k) * NN]);
                nrm0 = fmaf(f.x, f.x, nrm0);
                nrm1 = fmaf(f.y, f.y, nrm1);
                #pragma unroll
                for (int p = 0; p < PP; ++p) {
                    dot0[p] = fmaf(f.x, reinterpret_cast<const float*>(&pv0[p])[k], dot0[p]);
                    dot1[p] = fmaf(f.y, reinterpret_cast<const float*>(&pv1[p])[k], dot1[p]);
                }
            }
        }
        // write next chunk into the buffer nobody is reading, then barrier
        if (ch < 3) {
            #pragma unroll
            for (int r = 0; r < 5; ++r) {
                int idx = (r << 8) + tid;
                *reinterpret_cast<float4*>(
                    &lp[cur ^ 1][(idx >> 4) * LPAD + ((idx & 15) << 2)]) = stg[r];
            }
            __syncthreads();
        }
    }

    const float inv0 = 1.f / fmaxf(sqrtf(nrm0), 1e-12f);
    const float inv1 = 1.f / fmaxf(sqrtf(nrm1), 1e-12f);
    #pragma unroll
    for (int p = 0; p < PP; ++p) {
        float2 e;
        e.x = __expf(dot0[p] * inv0 - 1.f);   // fixed shift: sims in [-1,1]
        e.y = __expf(dot1[p] * inv1 - 1.f);
        *reinterpret_cast<float2*>(&plane[(size_t)(b * PP + p) * NN + n0]) = e;
        atomicAdd(&bins[cls.x * PP + p], e.x);
        atomicAdd(&bins[cls.y * PP + p], e.y);
    }
    atomicAdd(&binc[cls.x], 1.f);
    atomicAdd(&binc[cls.y], 1.f);
    __syncthreads();
    if (tid < CP) atomicAdd(&denom1[b * CP + tid], bins[tid]);
    if (tid < CC) atomicAdd(&cnt[b * CC + tid], binc[tid]);
}

// Pass 2: s1 = e1/denom1; u = exp(s1 - 1); denom2 += u.  4 pixels/thread.
__global__ __launch_bounds__(256) void k_s2(const int* __restrict__ gt,
                                            float* __restrict__ plane,
                                            const float* __restrict__ denom1,
                                            float* __restrict__ denom2) {
    __shared__ float inv1s[CP];
    __shared__ float bins[4][CP];          // replicated per warp
    const int tid = threadIdx.x;
    const int w   = tid >> 6;
    const int b   = blockIdx.x >> 6;       // 256 blocks: 64/batch
    const int n0  = ((blockIdx.x & 63) << 10) + (tid << 2);
    if (tid < CP) inv1s[tid] = 1.f / denom1[b * CP + tid];
    for (int i = tid; i < 4 * CP; i += 256) (&bins[0][0])[i] = 0.f;
    __syncthreads();
    const int4 cls = *reinterpret_cast<const int4*>(&gt[(size_t)b * NN + n0]);
    #pragma unroll
    for (int p = 0; p < PP; ++p) {
        size_t idx = (size_t)(b * PP + p) * NN + n0;
        float4 e = *reinterpret_cast<const float4*>(&plane[idx]);
        float4 u;
        u.x = __expf(e.x * inv1s[cls.x * PP + p] - 1.f);   // s1 in (0,1]
        u.y = __expf(e.y * inv1s[cls.y * PP + p] - 1.f);
        u.z = __expf(e.z * inv1s[cls.z * PP + p] - 1.f);
        u.w = __expf(e.w * inv1s[cls.w * PP + p] - 1.f);
        *reinterpret_cast<float4*>(&plane[idx]) = u;
        atomicAdd(&bins[w][cls.x * PP + p], u.x);
        atomicAdd(&bins[w][cls.y * PP + p], u.y);
        atomicAdd(&bins[w][cls.z * PP + p], u.z);
        atomicAdd(&bins[w][cls.w * PP + p], u.w);
    }
    __syncthreads();
    if (tid < CP)
        atomicAdd(&denom2[b * CP + tid],
                  bins[0][tid] + bins[1][tid] + bins[2][tid] + bins[3][tid]);
}

// Pass 3: V = u/denom2 + EPS; accumulate A_i = sum(L_i V_i) (5 slots) and
// S_ij = sum(L_i V_j + L_j V_i) for i<j (10 slots) per (b,c). 15 atomics/pixel.
__global__ __launch_bounds__(256) void k_bmat(const int* __restrict__ gt,
                                              const float* __restrict__ plane,
                                              const float* __restrict__ denom2,
                                              float* __restrict__ Bbins) {
    __shared__ float inv2s[CP];
    __shared__ float sb[4][CC * 16];       // replicated per warp
    const int tid = threadIdx.x;
    const int w   = tid >> 6;
    const int b   = blockIdx.x >> 6;
    const int n0  = ((blockIdx.x & 63) << 10) + (tid << 2);
    if (tid < CP) inv2s[tid] = 1.f / denom2[b * CP + tid];
    for (int i = tid; i < 4 * CC * 16; i += 256) (&sb[0][0])[i] = 0.f;
    __syncthreads();
    const int4 cls = *reinterpret_cast<const int4*>(&gt[(size_t)b * NN + n0]);
    const int c4[4] = {cls.x, cls.y, cls.z, cls.w};
    float V[4][PP], L[4][PP];
    #pragma unroll
    for (int p = 0; p < PP; ++p) {
        size_t idx = (size_t)(b * PP + p) * NN + n0;
        float4 u = *reinterpret_cast<const float4*>(&plane[idx]);
        V[0][p] = fmaf(u.x, inv2s[cls.x * PP + p], EPSV);
        V[1][p] = fmaf(u.y, inv2s[cls.y * PP + p], EPSV);
        V[2][p] = fmaf(u.z, inv2s[cls.z * PP + p], EPSV);
        V[3][p] = fmaf(u.w, inv2s[cls.w * PP + p], EPSV);
    }
    #pragma unroll
    for (int q = 0; q < 4; ++q)
        #pragma unroll
        for (int p = 0; p < PP; ++p) L[q][p] = __logf(V[q][p]);
    #pragma unroll
    for (int q = 0; q < 4; ++q) {
        float* base = &sb[w][c4[q] * 16];
        #pragma unroll
        for (int i = 0; i < PP; ++i) atomicAdd(&base[i], L[q][i] * V[q][i]);
        int slot = 5;
        #pragma unroll
        for (int i = 0; i < PP; ++i)
            #pragma unroll
            for (int j = i + 1; j < PP; ++j) {
                atomicAdd(&base[slot], fmaf(L[q][i], V[q][j], L[q][j] * V[q][i]));
                ++slot;
            }
    }
    __syncthreads();
    for (int i = tid; i < CC * 16; i += 256)
        atomicAdd(&Bbins[b * CC * 16 + i], sb[0][i] + sb[1][i] + sb[2][i] + sb[3][i]);
}

__global__ void k_final(const float* __restrict__ Bbins,
                        const float* __restrict__ cnt,
                        float* __restrict__ out) {
    __shared__ float cs[BB * CC];
    __shared__ float pr[BB * CC];
    const int t = threadIdx.x;
    if (t < BB * CC) {
        const float* bb = &Bbins[t * 16];
        float s = 0.f;
        int slot = 5;
        #pragma unroll
        for (int i = 0; i < PP; ++i)
            for (int j = i + 1; j < PP; ++j) {
                float J = bb[i] + bb[j] - bb[slot];   // A_i + A_j - S_ij
                ++slot;
                s += __expf(-J);
            }
        bool present = cnt[t] > 0.f;
        cs[t] = present ? s * 0.1f : 0.f;   // / num_pairs (=10)
        pr[t] = present ? 1.f : 0.f;
    }
    __syncthreads();
    if (t == 0) {
        float total = 0.f;
        for (int b = 0; b < BB; ++b) {
            float sc = 0.f, np = 0.f;
            for (int c = 0; c < CC; ++c) { sc += cs[b * CC + c]; np += pr[b * CC + c]; }
            total += (np > 0.f) ? sc / np : 0.f;
        }
        out[0] = total / (float)BB;
    }
}

extern "C" void kernel_launch(void* const* d_in, const int* in_sizes, int n_in,
                              void* d_out, int out_size, void* d_ws, size_t ws_size,
                              hipStream_t stream) {
    const float* fmap   = (const float*)d_in[0];
    const float* protos = (const float*)d_in[1];
    const int*   gt     = (const int*)d_in[2];
    float* ws      = (float*)d_ws;
    float* protosN = ws;
    float* plane   = ws + OFF_PLANE;
    float* acc     = ws + OFF_ACC;
    float* denom1  = acc;
    float* denom2  = acc + 320;
    float* cnt     = acc + 640;
    float* Bbins   = acc + 704;
    float* out     = (float*)d_out;

    k_norm <<<CP + 1, 256, 0, stream>>>(protos, protosN, acc);
    k_sims <<<512, 256, 0, stream>>>(fmap, protosN, gt, plane, denom1, cnt);
    k_s2   <<<256, 256, 0, stream>>>(gt, plane, denom1, denom2);
    k_bmat <<<256, 256, 0, stream>>>(gt, plane, denom2, Bbins);
    k_final<<<1, 64, 0, stream>>>(Bbins, cnt, out);
}

// Round 4
// 93.772 us; speedup vs baseline: 1.4887x; 1.0710x over previous
//
#include <hip/hip_runtime.h>
#include <math.h>

// Problem constants (fixed by setup_inputs)
#define BB 4
#define DD 256
#define NN 65536      // H*W
#define CC 16
#define PP 5
#define CP 80         // C*P
#define EPSV 1e-10f
#define PITCH 264     // bf16 units per proto row in LDS (pad 256->264)

// ws layout (floats):
//   protosN : [0, 20480)
//   plane   : [20480, +B*P*N)   holds e1 = exp(sim-1)
//   acc     : denom1[320] denom2[320] cnt[64] Bbins[B*C*16]
#define OFF_PLANE  20480
#define OFF_ACC    (OFF_PLANE + BB * PP * NN)
#define ACC_FLOATS (320 + 320 + 64 + BB * CC * 16)

__device__ __forceinline__ unsigned short f2bf(float f) {
    unsigned int u = __float_as_uint(f);
    u += 0x7fffu + ((u >> 16) & 1u);      // RNE
    return (unsigned short)(u >> 16);
}

// blocks 0..79: normalize prototype rows; block 80: zero accumulators
__global__ void k_norm(const float* __restrict__ protos,
                       float* __restrict__ protosN,
                       float* __restrict__ acc) {
    if (blockIdx.x == CP) {
        for (int i = threadIdx.x; i < ACC_FLOATS; i += 256) acc[i] = 0.f;
        return;
    }
    int r = blockIdx.x;
    int d = threadIdx.x;
    float v = protos[r * DD + d];
    __shared__ float red[256];
    red[d] = v * v;
    __syncthreads();
    for (int s = 128; s > 0; s >>= 1) {
        if (d < s) red[d] += red[d + s];
        __syncthreads();
    }
    float inv = 1.f / fmaxf(sqrtf(red[0]), 1e-12f);
    protosN[r * DD + d] = v * inv;
}

__device__ __forceinline__ void loadg(const float* __restrict__ fb, int g,
                                      float2 (&f)[8]) {
    const float* p = fb + (size_t)g * 8 * NN;
    #pragma unroll
    for (int k = 0; k < 8; ++k)
        f[k] = *reinterpret_cast<const float2*>(p + (size_t)k * NN);
}

__device__ __forceinline__ void comp(const char* lb0, const char* lb1,
                                     const float2 (&f)[8], int g,
                                     float (&d0)[PP], float (&d1)[PP],
                                     float& n0, float& n1) {
    uint4 q0[PP], q1[PP];
    #pragma unroll
    for (int p = 0; p < PP; ++p) {
        q0[p] = *reinterpret_cast<const uint4*>(lb0 + p * (PITCH * 2) + g * 16);
        q1[p] = *reinterpret_cast<const uint4*>(lb1 + p * (PITCH * 2) + g * 16);
    }
    #pragma unroll
    for (int k = 0; k < 8; ++k) {
        float fx = f[k].x, fy = f[k].y;
        n0 = fmaf(fx, fx, n0);
        n1 = fmaf(fy, fy, n1);
        #pragma unroll
        for (int p = 0; p < PP; ++p) {
            unsigned int w0 = (&q0[p].x)[k >> 1];
            unsigned int w1 = (&q1[p].x)[k >> 1];
            float a = __uint_as_float((k & 1) ? (w0 & 0xffff0000u) : (w0 << 16));
            float c = __uint_as_float((k & 1) ? (w1 & 0xffff0000u) : (w1 << 16));
            d0[p] = fmaf(fx, a, d0[p]);
            d1[p] = fmaf(fy, c, d1[p]);
        }
    }
}

// Pass 1: per-pixel normalized dot with its class's 5 prototypes.
// bf16 protos single-buffered in LDS (no mid-loop barriers); depth-2
// register pipeline of 8-d groups of float2 fmap loads (2 px/thread).
__global__ __launch_bounds__(256) void k_sims(const float* __restrict__ fmap,
                                              const float* __restrict__ protosN,
                                              const int* __restrict__ gt,
                                              float* __restrict__ plane,
                                              float* __restrict__ denom1,
                                              float* __restrict__ cnt) {
    __shared__ __align__(16) unsigned short lp[CP * PITCH];   // 42.24 KB
    __shared__ float bins[CP];
    __shared__ float binc[CC];
    const int tid = threadIdx.x;
    const int b   = blockIdx.x >> 7;                 // 512 blocks: 128/batch
    const int n0  = ((blockIdx.x & 127) << 9) + (tid << 1);

    if (tid < CP) bins[tid] = 0.f;
    if (tid < CC) binc[tid] = 0.f;

    // stage protos f32 -> bf16(RNE) into padded LDS, once
    for (int idx = tid; idx < 5120; idx += 256) {
        int cp = idx >> 6, q = idx & 63;
        float4 v = *reinterpret_cast<const float4*>(&protosN[(cp << 8) + (q << 2)]);
        unsigned int u0 = (unsigned int)f2bf(v.x) | ((unsigned int)f2bf(v.y) << 16);
        unsigned int u1 = (unsigned int)f2bf(v.z) | ((unsigned int)f2bf(v.w) << 16);
        *reinterpret_cast<uint2*>(reinterpret_cast<char*>(lp) + cp * (PITCH * 2) + (q << 3))
            = make_uint2(u0, u1);
    }
    __syncthreads();

    const int2 cls = *reinterpret_cast<const int2*>(&gt[(size_t)b * NN + n0]);
    const char* lb0 = reinterpret_cast<const char*>(lp) + cls.x * (PP * PITCH * 2);
    const char* lb1 = reinterpret_cast<const char*>(lp) + cls.y * (PP * PITCH * 2);
    const float* fb = fmap + (size_t)b * DD * NN + n0;

    float dot0[PP] = {0.f, 0.f, 0.f, 0.f, 0.f};
    float dot1[PP] = {0.f, 0.f, 0.f, 0.f, 0.f};
    float nrm0 = 0.f, nrm1 = 0.f;
    float2 fA[8], fB[8];

    loadg(fb, 0, fA);
    #pragma unroll 1
    for (int g = 0; g < 32; g += 2) {
        loadg(fb, g + 1, fB);
        comp(lb0, lb1, fA, g, dot0, dot1, nrm0, nrm1);
        if (g < 30) loadg(fb, g + 2, fA);
        comp(lb0, lb1, fB, g + 1, dot0, dot1, nrm0, nrm1);
    }

    const float inv0 = 1.f / fmaxf(sqrtf(nrm0), 1e-12f);
    const float inv1 = 1.f / fmaxf(sqrtf(nrm1), 1e-12f);
    #pragma unroll
    for (int p = 0; p < PP; ++p) {
        float2 e;
        e.x = __expf(dot0[p] * inv0 - 1.f);   // fixed shift: sims in [-1,1]
        e.y = __expf(dot1[p] * inv1 - 1.f);
        *reinterpret_cast<float2*>(&plane[(size_t)(b * PP + p) * NN + n0]) = e;
        atomicAdd(&bins[cls.x * PP + p], e.x);
        atomicAdd(&bins[cls.y * PP + p], e.y);
    }
    atomicAdd(&binc[cls.x], 1.f);
    atomicAdd(&binc[cls.y], 1.f);
    __syncthreads();
    if (tid < CP) atomicAdd(&denom1[b * CP + tid], bins[tid]);
    if (tid < CC) atomicAdd(&cnt[b * CC + tid], binc[tid]);
}

// Pass 2 (read-only): u = exp(e1/denom1 - 1); denom2 += u.  4 px/thread.
__global__ __launch_bounds__(256) void k_denom2(const int* __restrict__ gt,
                                                const float* __restrict__ plane,
                                                const float* __restrict__ denom1,
                                                float* __restrict__ denom2) {
    __shared__ float inv1s[CP];
    __shared__ float bins[4][CP];          // replicated per warp
    const int tid = threadIdx.x;
    const int w   = tid >> 6;
    const int b   = blockIdx.x >> 6;       // 256 blocks: 64/batch
    const int n0  = ((blockIdx.x & 63) << 10) + (tid << 2);
    if (tid < CP) inv1s[tid] = 1.f / denom1[b * CP + tid];
    for (int i = tid; i < 4 * CP; i += 256) (&bins[0][0])[i] = 0.f;
    __syncthreads();
    const int4 cls = *reinterpret_cast<const int4*>(&gt[(size_t)b * NN + n0]);
    #pragma unroll
    for (int p = 0; p < PP; ++p) {
        size_t idx = (size_t)(b * PP + p) * NN + n0;
        float4 e = *reinterpret_cast<const float4*>(&plane[idx]);
        atomicAdd(&bins[w][cls.x * PP + p], __expf(e.x * inv1s[cls.x * PP + p] - 1.f));
        atomicAdd(&bins[w][cls.y * PP + p], __expf(e.y * inv1s[cls.y * PP + p] - 1.f));
        atomicAdd(&bins[w][cls.z * PP + p], __expf(e.z * inv1s[cls.z * PP + p] - 1.f));
        atomicAdd(&bins[w][cls.w * PP + p], __expf(e.w * inv1s[cls.w * PP + p] - 1.f));
    }
    __syncthreads();
    if (tid < CP)
        atomicAdd(&denom2[b * CP + tid],
                  bins[0][tid] + bins[1][tid] + bins[2][tid] + bins[3][tid]);
}

// Pass 3: recompute u from e1 (bit-identical), V = u/denom2 + EPS;
// accumulate A_i (5) and S_ij = L_iV_j + L_jV_i (10) per (b,c).
__global__ __launch_bounds__(256) void k_bmat(const int* __restrict__ gt,
                                              const float* __restrict__ plane,
                                              const float* __restrict__ denom1,
                                              const float* __restrict__ denom2,
                                              float* __restrict__ Bbins) {
    __shared__ float inv1s[CP];
    __shared__ float inv2s[CP];
    __shared__ float sb[4][CC * 16];       // replicated per warp
    const int tid = threadIdx.x;
    const int w   = tid >> 6;
    const int b   = blockIdx.x >> 6;
    const int n0  = ((blockIdx.x & 63) << 10) + (tid << 2);
    if (tid < CP) {
        inv1s[tid] = 1.f / denom1[b * CP + tid];
        inv2s[tid] = 1.f / denom2[b * CP + tid];
    }
    for (int i = tid; i < 4 * CC * 16; i += 256) (&sb[0][0])[i] = 0.f;
    __syncthreads();
    const int4 cls = *reinterpret_cast<const int4*>(&gt[(size_t)b * NN + n0]);
    const int c4[4] = {cls.x, cls.y, cls.z, cls.w};
    float V[4][PP], L[4][PP];
    #pragma unroll
    for (int p = 0; p < PP; ++p) {
        size_t idx = (size_t)(b * PP + p) * NN + n0;
        float4 e = *reinterpret_cast<const float4*>(&plane[idx]);
        V[0][p] = fmaf(__expf(e.x * inv1s[cls.x * PP + p] - 1.f), inv2s[cls.x * PP + p], EPSV);
        V[1][p] = fmaf(__expf(e.y * inv1s[cls.y * PP + p] - 1.f), inv2s[cls.y * PP + p], EPSV);
        V[2][p] = fmaf(__expf(e.z * inv1s[cls.z * PP + p] - 1.f), inv2s[cls.z * PP + p], EPSV);
        V[3][p] = fmaf(__expf(e.w * inv1s[cls.w * PP + p] - 1.f), inv2s[cls.w * PP + p], EPSV);
    }
    #pragma unroll
    for (int q = 0; q < 4; ++q)
        #pragma unroll
        for (int p = 0; p < PP; ++p) L[q][p] = __logf(V[q][p]);
    #pragma unroll
    for (int q = 0; q < 4; ++q) {
        float* base = &sb[w][c4[q] * 16];
        #pragma unroll
        for (int i = 0; i < PP; ++i) atomicAdd(&base[i], L[q][i] * V[q][i]);
        int slot = 5;
        #pragma unroll
        for (int i = 0; i < PP; ++i)
            #pragma unroll
            for (int j = i + 1; j < PP; ++j) {
                atomicAdd(&base[slot], fmaf(L[q][i], V[q][j], L[q][j] * V[q][i]));
                ++slot;
            }
    }
    __syncthreads();
    for (int i = tid; i < CC * 16; i += 256)
        atomicAdd(&Bbins[b * CC * 16 + i], sb[0][i] + sb[1][i] + sb[2][i] + sb[3][i]);
}

__global__ void k_final(const float* __restrict__ Bbins,
                        const float* __restrict__ cnt,
                        float* __restrict__ out) {
    __shared__ float cs[BB * CC];
    __shared__ float pr[BB * CC];
    const int t = threadIdx.x;
    if (t < BB * CC) {
        const float* bb = &Bbins[t * 16];
        float s = 0.f;
        int slot = 5;
        #pragma unroll
        for (int i = 0; i < PP; ++i)
            for (int j = i + 1; j < PP; ++j) {
                float J = bb[i] + bb[j] - bb[slot];   // A_i + A_j - S_ij
                ++slot;
                s += __expf(-J);
            }
        bool present = cnt[t] > 0.f;
        cs[t] = present ? s * 0.1f : 0.f;   // / num_pairs (=10)
        pr[t] = present ? 1.f : 0.f;
    }
    __syncthreads();
    if (t == 0) {
        float total = 0.f;
        for (int b = 0; b < BB; ++b) {
            float sc = 0.f, np = 0.f;
            for (int c = 0; c < CC; ++c) { sc += cs[b * CC + c]; np += pr[b * CC + c]; }
            total += (np > 0.f) ? sc / np : 0.f;
        }
        out[0] = total / (float)BB;
    }
}

extern "C" void kernel_launch(void* const* d_in, const int* in_sizes, int n_in,
                              void* d_out, int out_size, void* d_ws, size_t ws_size,
                              hipStream_t stream) {
    const float* fmap   = (const float*)d_in[0];
    const float* protos = (const float*)d_in[1];
    const int*   gt     = (const int*)d_in[2];
    float* ws      = (float*)d_ws;
    float* protosN = ws;
    float* plane   = ws + OFF_PLANE;
    float* acc     = ws + OFF_ACC;
    float* denom1  = acc;
    float* denom2  = acc + 320;
    float* cnt     = acc + 640;
    float* Bbins   = acc + 704;
    float* out     = (float*)d_out;

    k_norm  <<<CP + 1, 256, 0, stream>>>(protos, protosN, acc);
    k_sims  <<<512, 256, 0, stream>>>(fmap, protosN, gt, plane, denom1, cnt);
    k_denom2<<<256, 256, 0, stream>>>(gt, plane, denom1, denom2);
    k_bmat  <<<256, 256, 0, stream>>>(gt, plane, denom1, denom2, Bbins);
    k_final <<<1, 64, 0, stream>>>(Bbins, cnt, out);
}